// Round 1
// baseline (1053.240 us; speedup 1.0000x reference)
//
#include <hip/hip_runtime.h>
#include <hip/hip_bf16.h>

// Problem constants (static per reference)
#define D 128
#define H 64
#define R 4
#define NT 64      // nodes per tile/block
#define LDC 132    // LDS stride for 128-wide chunks (+4 floats: bank stagger, 16B-aligned rows)
#define LDH 68     // LDS stride for 64-wide hidden (+4 floats)

__device__ __forceinline__ float4 relu4(float4 v) {
    return make_float4(fmaxf(v.x, 0.f), fmaxf(v.y, 0.f), fmaxf(v.z, 0.f), fmaxf(v.w, 0.f));
}

// Accumulate a [4 nodes x 4 cols] register tile over K contraction dims.
// Wg: global weights [K][ldw] row-major, columns j4..j4+3.
// Xl: LDS rows for the 4 nodes, stride ldx (row base pre-offset to node nb).
__device__ __forceinline__ void gemm_acc(float (&acc)[4][4], const float* __restrict__ Wg,
                                         int ldw, const float* Xl, int ldx, int K, int j4) {
    for (int k = 0; k < K; k += 4) {
        float4 w0 = *(const float4*)&Wg[(k + 0) * ldw + j4];
        float4 w1 = *(const float4*)&Wg[(k + 1) * ldw + j4];
        float4 w2 = *(const float4*)&Wg[(k + 2) * ldw + j4];
        float4 w3 = *(const float4*)&Wg[(k + 3) * ldw + j4];
#pragma unroll
        for (int ni = 0; ni < 4; ++ni) {
            float4 x = *(const float4*)&Xl[ni * ldx + k];
            acc[ni][0] += x.x * w0.x + x.y * w1.x + x.z * w2.x + x.w * w3.x;
            acc[ni][1] += x.x * w0.y + x.y * w1.y + x.z * w2.y + x.w * w3.y;
            acc[ni][2] += x.x * w0.z + x.y * w1.z + x.z * w2.z + x.w * w3.z;
            acc[ni][3] += x.x * w0.w + x.y * w1.w + x.z * w2.w + x.w * w3.w;
        }
    }
}

// ---------------- CSR build ----------------

__global__ __launch_bounds__(256) void k_count(const int* __restrict__ dst, int* __restrict__ cnt, int E) {
    int e = blockIdx.x * 256 + threadIdx.x;
    if (e < E) atomicAdd(&cnt[dst[e]], 1);
}

__global__ __launch_bounds__(1024) void k_scan(const int* __restrict__ cnt, int* __restrict__ offs,
                                               int* __restrict__ cursor, int N) {
    __shared__ int sums[1024];
    int tid = threadIdx.x;
    int per = (N + 1023) / 1024;
    int start = tid * per;
    int end = start + per; if (end > N) end = N; if (start > N) start = N;
    int s = 0;
    for (int i = start; i < end; ++i) s += cnt[i];
    sums[tid] = s;
    __syncthreads();
    for (int off = 1; off < 1024; off <<= 1) {
        int v = (tid >= off) ? sums[tid - off] : 0;
        __syncthreads();
        sums[tid] += v;
        __syncthreads();
    }
    int run = sums[tid] - s;  // exclusive prefix of this thread's chunk
    for (int i = start; i < end; ++i) {
        offs[i] = run;
        cursor[i] = run;
        run += cnt[i];
    }
}

__global__ __launch_bounds__(256) void k_fill(const int* __restrict__ src, const int* __restrict__ dst,
                                              const int* __restrict__ etype, int* __restrict__ cursor,
                                              int* __restrict__ eidx, int E) {
    int e = blockIdx.x * 256 + threadIdx.x;
    if (e < E) {
        int d = dst[e];
        int p = atomicAdd(&cursor[d], 1);
        eidx[p] = src[e] * 4 + etype[e];   // = T row index directly
    }
}

// ---------------- Stage A: per-(node, relation) message MLP ----------------
// T[(n*R + r)*D + d] = relu(MLP_r(x_n))[d]

__global__ __launch_bounds__(256) void k_mlp_rel(
    const float* __restrict__ X,
    const float* __restrict__ W1, const float* __restrict__ b1,
    const float* __restrict__ W2, const float* __restrict__ b2,
    const float* __restrict__ W3, const float* __restrict__ b3,
    float* __restrict__ T, int N)
{
    __shared__ float Xs[NT * LDC];   // X tile; reused as H2 (stride LDC) in layer 3
    __shared__ float Hs[NT * LDH];   // H1

    const int tid = threadIdx.x;
    const int r = blockIdx.x & 3;
    const int n0 = (blockIdx.x >> 2) * NT;

    const float* W1r = W1 + r * (D * H);
    const float* b1r = b1 + r * H;
    const float* W2r = W2 + r * (H * H);
    const float* b2r = b2 + r * H;
    const float* W3r = W3 + r * (H * D);
    const float* b3r = b3 + r * D;

    // load X tile (zero-pad past N)
    for (int idx = tid; idx < NT * 32; idx += 256) {
        int row = idx >> 5;
        int c4 = (idx & 31) << 2;
        int n = n0 + row;
        float4 v = make_float4(0.f, 0.f, 0.f, 0.f);
        if (n < N) v = *(const float4*)&X[(size_t)n * D + c4];
        *(float4*)&Xs[row * LDC + c4] = v;
    }
    __syncthreads();

    const int j4 = (tid & 15) << 2;   // 0..60
    const int nb = (tid >> 4) << 2;   // 0..60

    // layer 1: 128 -> 64
    float acc1[4][4];
#pragma unroll
    for (int jj = 0; jj < 4; ++jj) {
        float bv = b1r[j4 + jj];
        acc1[0][jj] = bv; acc1[1][jj] = bv; acc1[2][jj] = bv; acc1[3][jj] = bv;
    }
    gemm_acc(acc1, W1r, H, &Xs[nb * LDC], LDC, D, j4);
#pragma unroll
    for (int ni = 0; ni < 4; ++ni) {
        float4 h = relu4(make_float4(acc1[ni][0], acc1[ni][1], acc1[ni][2], acc1[ni][3]));
        *(float4*)&Hs[(nb + ni) * LDH + j4] = h;
    }
    __syncthreads();

    // layer 2: 64 -> 64 (write H2 into Xs region)
    float acc2[4][4];
#pragma unroll
    for (int jj = 0; jj < 4; ++jj) {
        float bv = b2r[j4 + jj];
        acc2[0][jj] = bv; acc2[1][jj] = bv; acc2[2][jj] = bv; acc2[3][jj] = bv;
    }
    gemm_acc(acc2, W2r, H, &Hs[nb * LDH], LDH, H, j4);
#pragma unroll
    for (int ni = 0; ni < 4; ++ni) {
        float4 h = relu4(make_float4(acc2[ni][0], acc2[ni][1], acc2[ni][2], acc2[ni][3]));
        *(float4*)&Xs[(nb + ni) * LDC + j4] = h;
    }
    __syncthreads();

    // layer 3: 64 -> 128, outer relu, store T
#pragma unroll
    for (int half = 0; half < 2; ++half) {
        int nb3 = ((tid >> 5) << 2) + (half << 5);
        int j43 = (tid & 31) << 2;
        float acc3[4][4];
#pragma unroll
        for (int jj = 0; jj < 4; ++jj) {
            float bv = b3r[j43 + jj];
            acc3[0][jj] = bv; acc3[1][jj] = bv; acc3[2][jj] = bv; acc3[3][jj] = bv;
        }
        gemm_acc(acc3, W3r, D, &Xs[nb3 * LDC], LDC, H, j43);
#pragma unroll
        for (int ni = 0; ni < 4; ++ni) {
            int n = n0 + nb3 + ni;
            if (n < N) {
                float4 o = relu4(make_float4(acc3[ni][0], acc3[ni][1], acc3[ni][2], acc3[ni][3]));
                *(float4*)&T[((size_t)n * R + r) * D + j43] = o;
            }
        }
    }
}

// ---------------- Stage B+C fused: aggregate + updater MLP + select ----------------

__global__ __launch_bounds__(256) void k_agg_upd(
    const float* __restrict__ X, const float* __restrict__ T,
    const int* __restrict__ cnt, const int* __restrict__ offs, const int* __restrict__ eidx,
    const int* __restrict__ node_type,
    const float* __restrict__ Wu1, const float* __restrict__ bu1,
    const float* __restrict__ Wu2, const float* __restrict__ bu2,
    const float* __restrict__ Wu3, const float* __restrict__ bu3,
    float* __restrict__ out, int N)
{
    __shared__ float Cs[NT * LDC];   // enc chunk; reused as H2 in layer 3
    __shared__ float Hs[NT * LDH];   // H1

    const int tid = threadIdx.x;
    const int n0 = blockIdx.x * NT;
    const int j4 = (tid & 15) << 2;
    const int nb = (tid >> 4) << 2;

    // layer-1 accumulator lives across the 5 enc chunks
    float acc1[4][4];
#pragma unroll
    for (int jj = 0; jj < 4; ++jj) {
        float bv = bu1[j4 + jj];
        acc1[0][jj] = bv; acc1[1][jj] = bv; acc1[2][jj] = bv; acc1[3][jj] = bv;
    }

    for (int c = 0; c < 5; ++c) {
        if (c == 0) {
            // enc block 0: relu(x) * (indeg > 0)
            for (int idx = tid; idx < NT * 32; idx += 256) {
                int row = idx >> 5;
                int c4 = (idx & 31) << 2;
                int n = n0 + row;
                float4 v = make_float4(0.f, 0.f, 0.f, 0.f);
                if (n < N && cnt[n] > 0)
                    v = relu4(*(const float4*)&X[(size_t)n * D + c4]);
                *(float4*)&Cs[row * LDC + c4] = v;
            }
        } else {
            // enc block c: sum of T rows for edges of relation r into this dst
            int r = c - 1;
            int wid = tid >> 6, lane = tid & 63;
            for (int nl = wid; nl < NT; nl += 4) {
                int n = n0 + nl;
                float2 a = make_float2(0.f, 0.f);
                if (n < N) {
                    int s = offs[n], e = s + cnt[n];
                    for (int i = s; i < e; ++i) {
                        int v = eidx[i];
                        if ((v & 3) == r) {
                            float2 t2 = *(const float2*)&T[(size_t)v * D + (lane << 1)];
                            a.x += t2.x; a.y += t2.y;
                        }
                    }
                }
                *(float2*)&Cs[nl * LDC + (lane << 1)] = a;
            }
        }
        __syncthreads();
        gemm_acc(acc1, Wu1 + c * (D * H), H, &Cs[nb * LDC], LDC, D, j4);
        __syncthreads();   // before next chunk overwrites Cs
    }

#pragma unroll
    for (int ni = 0; ni < 4; ++ni) {
        float4 h = relu4(make_float4(acc1[ni][0], acc1[ni][1], acc1[ni][2], acc1[ni][3]));
        *(float4*)&Hs[(nb + ni) * LDH + j4] = h;
    }
    __syncthreads();

    // layer 2: 64 -> 64
    float acc2[4][4];
#pragma unroll
    for (int jj = 0; jj < 4; ++jj) {
        float bv = bu2[j4 + jj];
        acc2[0][jj] = bv; acc2[1][jj] = bv; acc2[2][jj] = bv; acc2[3][jj] = bv;
    }
    gemm_acc(acc2, Wu2, H, &Hs[nb * LDH], LDH, H, j4);
#pragma unroll
    for (int ni = 0; ni < 4; ++ni) {
        float4 h = relu4(make_float4(acc2[ni][0], acc2[ni][1], acc2[ni][2], acc2[ni][3]));
        *(float4*)&Cs[(nb + ni) * LDC + j4] = h;
    }
    __syncthreads();

    // layer 3: 64 -> 128 (linear), then select by node_type
#pragma unroll
    for (int half = 0; half < 2; ++half) {
        int nb3 = ((tid >> 5) << 2) + (half << 5);
        int j43 = (tid & 31) << 2;
        float acc3[4][4];
#pragma unroll
        for (int jj = 0; jj < 4; ++jj) {
            float bv = bu3[j43 + jj];
            acc3[0][jj] = bv; acc3[1][jj] = bv; acc3[2][jj] = bv; acc3[3][jj] = bv;
        }
        gemm_acc(acc3, Wu3, D, &Cs[nb3 * LDC], LDC, H, j43);
#pragma unroll
        for (int ni = 0; ni < 4; ++ni) {
            int n = n0 + nb3 + ni;
            if (n < N) {
                int t = node_type[n];
                float4 o;
                if (t <= 1) {   // UPDATE_NODE_TYPES = (0,1); types are 0..2
                    o = make_float4(acc3[ni][0], acc3[ni][1], acc3[ni][2], acc3[ni][3]);
                } else {
                    o = *(const float4*)&X[(size_t)n * D + j43];
                }
                *(float4*)&out[(size_t)n * D + j43] = o;
            }
        }
    }
}

extern "C" void kernel_launch(void* const* d_in, const int* in_sizes, int n_in,
                              void* d_out, int out_size, void* d_ws, size_t ws_size,
                              hipStream_t stream) {
    const float* X     = (const float*)d_in[0];
    const int*   src   = (const int*)d_in[1];
    const int*   dst   = (const int*)d_in[2];
    const int*   etype = (const int*)d_in[3];
    const int*   ntype = (const int*)d_in[4];
    const float* W1    = (const float*)d_in[5];
    const float* b1    = (const float*)d_in[6];
    const float* W2    = (const float*)d_in[7];
    const float* b2    = (const float*)d_in[8];
    const float* W3    = (const float*)d_in[9];
    const float* b3    = (const float*)d_in[10];
    const float* Wu1   = (const float*)d_in[11];
    const float* bu1   = (const float*)d_in[12];
    const float* Wu2   = (const float*)d_in[13];
    const float* bu2   = (const float*)d_in[14];
    const float* Wu3   = (const float*)d_in[15];
    const float* bu3   = (const float*)d_in[16];
    float* out = (float*)d_out;

    const int N = in_sizes[4];   // node_type length
    const int E = in_sizes[1];   // src length

    // workspace layout
    float* T    = (float*)d_ws;                       // N * R * D floats (102.4 MB)
    int* cnt    = (int*)(T + (size_t)N * R * D);      // N
    int* offs   = cnt + N;                            // N
    int* cursor = offs + N;                           // N
    int* eidx   = cursor + N;                         // E

    hipMemsetAsync(cnt, 0, (size_t)N * sizeof(int), stream);

    int eb = (E + 255) / 256;
    k_count<<<eb, 256, 0, stream>>>(dst, cnt, E);
    k_scan<<<1, 1024, 0, stream>>>(cnt, offs, cursor, N);
    k_fill<<<eb, 256, 0, stream>>>(src, dst, etype, cursor, eidx, E);

    int tiles = (N + NT - 1) / NT;
    k_mlp_rel<<<tiles * R, 256, 0, stream>>>(X, W1, b1, W2, b2, W3, b3, T, N);
    k_agg_upd<<<tiles, 256, 0, stream>>>(X, T, cnt, offs, eidx, ntype,
                                         Wu1, bu1, Wu2, bu2, Wu3, bu3, out, N);
}

// Round 3
// 466.147 us; speedup vs baseline: 2.2595x; 2.2595x over previous
//
#include <hip/hip_runtime.h>
#include <hip/hip_bf16.h>

// Problem constants (static per reference)
#define D 128
#define H 64
#define R 4
#define NT 64      // nodes per tile/block
#define LDC 132    // LDS stride for 128-wide chunks (+4 floats: bank stagger, 16B-aligned rows)
#define LDH 68     // LDS stride for 64-wide hidden (+4 floats)

__device__ __forceinline__ float4 relu4(float4 v) {
    return make_float4(fmaxf(v.x, 0.f), fmaxf(v.y, 0.f), fmaxf(v.z, 0.f), fmaxf(v.w, 0.f));
}

// Accumulate a [4 nodes x 4 cols] register tile over K contraction dims.
__device__ __forceinline__ void gemm_acc(float (&acc)[4][4], const float* __restrict__ Wg,
                                         int ldw, const float* Xl, int ldx, int K, int j4) {
    for (int k = 0; k < K; k += 4) {
        float4 w0 = *(const float4*)&Wg[(k + 0) * ldw + j4];
        float4 w1 = *(const float4*)&Wg[(k + 1) * ldw + j4];
        float4 w2 = *(const float4*)&Wg[(k + 2) * ldw + j4];
        float4 w3 = *(const float4*)&Wg[(k + 3) * ldw + j4];
#pragma unroll
        for (int ni = 0; ni < 4; ++ni) {
            float4 x = *(const float4*)&Xl[ni * ldx + k];
            acc[ni][0] += x.x * w0.x + x.y * w1.x + x.z * w2.x + x.w * w3.x;
            acc[ni][1] += x.x * w0.y + x.y * w1.y + x.z * w2.y + x.w * w3.y;
            acc[ni][2] += x.x * w0.z + x.y * w1.z + x.z * w2.z + x.w * w3.z;
            acc[ni][3] += x.x * w0.w + x.y * w1.w + x.z * w2.w + x.w * w3.w;
        }
    }
}

// ---------------- CSR build ----------------

__global__ __launch_bounds__(256) void k_count(const int* __restrict__ dst, int* __restrict__ cnt, int E) {
    int e = blockIdx.x * 256 + threadIdx.x;
    if (e < E) atomicAdd(&cnt[dst[e]], 1);
}

__global__ __launch_bounds__(1024) void k_scan(const int* __restrict__ cnt, int* __restrict__ offs,
                                               int* __restrict__ cursor, int N) {
    __shared__ int sums[1024];
    int tid = threadIdx.x;
    int per = (N + 1023) / 1024;
    int start = tid * per;
    int end = start + per; if (end > N) end = N; if (start > N) start = N;
    int s = 0;
    for (int i = start; i < end; ++i) s += cnt[i];
    sums[tid] = s;
    __syncthreads();
    for (int off = 1; off < 1024; off <<= 1) {
        int v = (tid >= off) ? sums[tid - off] : 0;
        __syncthreads();
        sums[tid] += v;
        __syncthreads();
    }
    int run = sums[tid] - s;  // exclusive prefix of this thread's chunk
    for (int i = start; i < end; ++i) {
        offs[i] = run;
        cursor[i] = run;
        run += cnt[i];
    }
}

__global__ __launch_bounds__(256) void k_fill(const int* __restrict__ src, const int* __restrict__ dst,
                                              const int* __restrict__ etype, int* __restrict__ cursor,
                                              int* __restrict__ eidx, int E) {
    int e = blockIdx.x * 256 + threadIdx.x;
    if (e < E) {
        int d = dst[e];
        int p = atomicAdd(&cursor[d], 1);
        eidx[p] = src[e] * 4 + etype[e];   // = U row index directly
    }
}

// ---------------- Stage A: per-(node, relation) message MLP + Wu1 fold ----------------
// U[(n*R + r)*H + j] = relu(MLP_r(x_n)) @ Wu1_{r+1}   (T never materialized)

__global__ __launch_bounds__(256) void k_mlp_rel(
    const float* __restrict__ X,
    const float* __restrict__ W1, const float* __restrict__ b1,
    const float* __restrict__ W2, const float* __restrict__ b2,
    const float* __restrict__ W3, const float* __restrict__ b3,
    const float* __restrict__ Wu1,
    float* __restrict__ U, int N)
{
    __shared__ float Xs[NT * LDC];   // X tile; reused as H2, then as T tile
    __shared__ float Hs[NT * LDH];   // H1

    const int tid = threadIdx.x;
    const int r = blockIdx.x & 3;
    const int n0 = (blockIdx.x >> 2) * NT;

    const float* W1r = W1 + r * (D * H);
    const float* b1r = b1 + r * H;
    const float* W2r = W2 + r * (H * H);
    const float* b2r = b2 + r * H;
    const float* W3r = W3 + r * (H * D);
    const float* b3r = b3 + r * D;
    const float* Wu1r = Wu1 + (size_t)(r + 1) * D * H;  // layer-1 chunk for this relation

    // load X tile (zero-pad past N)
    for (int idx = tid; idx < NT * 32; idx += 256) {
        int row = idx >> 5;
        int c4 = (idx & 31) << 2;
        int n = n0 + row;
        float4 v = make_float4(0.f, 0.f, 0.f, 0.f);
        if (n < N) v = *(const float4*)&X[(size_t)n * D + c4];
        *(float4*)&Xs[row * LDC + c4] = v;
    }
    __syncthreads();

    const int j4 = (tid & 15) << 2;   // 0..60
    const int nb = (tid >> 4) << 2;   // 0..60

    // layer 1: 128 -> 64
    float acc1[4][4];
#pragma unroll
    for (int jj = 0; jj < 4; ++jj) {
        float bv = b1r[j4 + jj];
        acc1[0][jj] = bv; acc1[1][jj] = bv; acc1[2][jj] = bv; acc1[3][jj] = bv;
    }
    gemm_acc(acc1, W1r, H, &Xs[nb * LDC], LDC, D, j4);
#pragma unroll
    for (int ni = 0; ni < 4; ++ni) {
        float4 h = relu4(make_float4(acc1[ni][0], acc1[ni][1], acc1[ni][2], acc1[ni][3]));
        *(float4*)&Hs[(nb + ni) * LDH + j4] = h;
    }
    __syncthreads();

    // layer 2: 64 -> 64 (write H2 into Xs region)
    float acc2[4][4];
#pragma unroll
    for (int jj = 0; jj < 4; ++jj) {
        float bv = b2r[j4 + jj];
        acc2[0][jj] = bv; acc2[1][jj] = bv; acc2[2][jj] = bv; acc2[3][jj] = bv;
    }
    gemm_acc(acc2, W2r, H, &Hs[nb * LDH], LDH, H, j4);
#pragma unroll
    for (int ni = 0; ni < 4; ++ni) {
        float4 h = relu4(make_float4(acc2[ni][0], acc2[ni][1], acc2[ni][2], acc2[ni][3]));
        *(float4*)&Xs[(nb + ni) * LDC + j4] = h;
    }
    __syncthreads();

    // layer 3: 64 -> 128, outer relu -> T tile (registers first, then back into Xs)
    float acc3[2][4][4];
#pragma unroll
    for (int half = 0; half < 2; ++half) {
        int nb3 = ((tid >> 5) << 2) + (half << 5);
        int j43 = (tid & 31) << 2;
#pragma unroll
        for (int jj = 0; jj < 4; ++jj) {
            float bv = b3r[j43 + jj];
            acc3[half][0][jj] = bv; acc3[half][1][jj] = bv;
            acc3[half][2][jj] = bv; acc3[half][3][jj] = bv;
        }
        gemm_acc(acc3[half], W3r, D, &Xs[nb3 * LDC], LDC, H, j43);
    }
    __syncthreads();   // all reads of H2 done; Xs free
#pragma unroll
    for (int half = 0; half < 2; ++half) {
        int nb3 = ((tid >> 5) << 2) + (half << 5);
        int j43 = (tid & 31) << 2;
#pragma unroll
        for (int ni = 0; ni < 4; ++ni) {
            float4 o = relu4(make_float4(acc3[half][ni][0], acc3[half][ni][1],
                                         acc3[half][ni][2], acc3[half][ni][3]));
            *(float4*)&Xs[(nb3 + ni) * LDC + j43] = o;   // T tile, 64 x 128
        }
    }
    __syncthreads();

    // U projection: T(64x128) @ Wu1_{r+1}(128x64), linear (bias added in k_upd)
    float accu[4][4];
#pragma unroll
    for (int jj = 0; jj < 4; ++jj) {
        accu[0][jj] = 0.f; accu[1][jj] = 0.f; accu[2][jj] = 0.f; accu[3][jj] = 0.f;
    }
    gemm_acc(accu, Wu1r, H, &Xs[nb * LDC], LDC, D, j4);
#pragma unroll
    for (int ni = 0; ni < 4; ++ni) {
        int n = n0 + nb + ni;
        if (n < N) {
            *(float4*)&U[((size_t)n * R + r) * H + j4] =
                make_float4(accu[ni][0], accu[ni][1], accu[ni][2], accu[ni][3]);
        }
    }
}

// ---------------- Stage B: gather S[n] = sum over in-edges of U[src*4+rel] ----------------

__global__ __launch_bounds__(256) void k_gather(
    const float* __restrict__ U,
    const int* __restrict__ cnt, const int* __restrict__ offs, const int* __restrict__ eidx,
    float* __restrict__ S, int N)
{
    const int wid = threadIdx.x >> 6, lane = threadIdx.x & 63;
    const int n = blockIdx.x * 4 + wid;
    if (n >= N) return;
    const int g = cnt[n];
    const int s = offs[n];
    float acc = 0.f;
    for (int base = 0; base < g; base += 64) {
        int m = g - base; if (m > 64) m = 64;
        int v = 0;
        if (lane < m) v = eidx[s + base + lane];
        for (int j0 = 0; j0 < m; j0 += 8) {
            int lim = m - j0; if (lim > 8) lim = 8;
            float t[8];
#pragma unroll
            for (int j = 0; j < 8; ++j) {
                int vi = __shfl(v, j0 + j);                 // uniform broadcast
                t[j] = (j < lim) ? U[(size_t)vi * H + lane] : 0.f;  // 8 loads in flight
            }
#pragma unroll
            for (int j = 0; j < 8; ++j) acc += t[j];
        }
    }
    S[(size_t)n * H + lane] = acc;
}

// ---------------- Stage C: updater MLP + select ----------------

__global__ __launch_bounds__(256) void k_upd(
    const float* __restrict__ X, const float* __restrict__ S,
    const int* __restrict__ cnt, const int* __restrict__ node_type,
    const float* __restrict__ Wu1, const float* __restrict__ bu1,
    const float* __restrict__ Wu2, const float* __restrict__ bu2,
    const float* __restrict__ Wu3, const float* __restrict__ bu3,
    float* __restrict__ out, int N)
{
    __shared__ float Xs[NT * LDC];   // relu(x)*has_in tile; reused as H2
    __shared__ float Hs[NT * LDH];   // H1

    const int tid = threadIdx.x;
    const int n0 = blockIdx.x * NT;
    const int j4 = (tid & 15) << 2;
    const int nb = (tid >> 4) << 2;

    // load enc chunk 0: relu(x) * (indeg > 0)
    for (int idx = tid; idx < NT * 32; idx += 256) {
        int row = idx >> 5;
        int c4 = (idx & 31) << 2;
        int n = n0 + row;
        float4 v = make_float4(0.f, 0.f, 0.f, 0.f);
        if (n < N && cnt[n] > 0)
            v = relu4(*(const float4*)&X[(size_t)n * D + c4]);
        *(float4*)&Xs[row * LDC + c4] = v;
    }
    __syncthreads();

    // layer 1: bu1 + S + chunk0 @ Wu1[0:128]
    float acc1[4][4];
#pragma unroll
    for (int ni = 0; ni < 4; ++ni) {
        int n = n0 + nb + ni;
        float4 sv = make_float4(0.f, 0.f, 0.f, 0.f);
        if (n < N) sv = *(const float4*)&S[(size_t)n * H + j4];
        acc1[ni][0] = bu1[j4 + 0] + sv.x;
        acc1[ni][1] = bu1[j4 + 1] + sv.y;
        acc1[ni][2] = bu1[j4 + 2] + sv.z;
        acc1[ni][3] = bu1[j4 + 3] + sv.w;
    }
    gemm_acc(acc1, Wu1, H, &Xs[nb * LDC], LDC, D, j4);
#pragma unroll
    for (int ni = 0; ni < 4; ++ni) {
        float4 h = relu4(make_float4(acc1[ni][0], acc1[ni][1], acc1[ni][2], acc1[ni][3]));
        *(float4*)&Hs[(nb + ni) * LDH + j4] = h;
    }
    __syncthreads();

    // layer 2: 64 -> 64
    float acc2[4][4];
#pragma unroll
    for (int jj = 0; jj < 4; ++jj) {
        float bv = bu2[j4 + jj];
        acc2[0][jj] = bv; acc2[1][jj] = bv; acc2[2][jj] = bv; acc2[3][jj] = bv;
    }
    gemm_acc(acc2, Wu2, H, &Hs[nb * LDH], LDH, H, j4);
#pragma unroll
    for (int ni = 0; ni < 4; ++ni) {
        float4 h = relu4(make_float4(acc2[ni][0], acc2[ni][1], acc2[ni][2], acc2[ni][3]));
        *(float4*)&Xs[(nb + ni) * LDC + j4] = h;
    }
    __syncthreads();

    // layer 3: 64 -> 128 (linear), then select by node_type
#pragma unroll
    for (int half = 0; half < 2; ++half) {
        int nb3 = ((tid >> 5) << 2) + (half << 5);
        int j43 = (tid & 31) << 2;
        float acc3[4][4];
#pragma unroll
        for (int jj = 0; jj < 4; ++jj) {
            float bv = bu3[j43 + jj];
            acc3[0][jj] = bv; acc3[1][jj] = bv; acc3[2][jj] = bv; acc3[3][jj] = bv;
        }
        gemm_acc(acc3, Wu3, D, &Xs[nb3 * LDC], LDC, H, j43);
#pragma unroll
        for (int ni = 0; ni < 4; ++ni) {
            int n = n0 + nb3 + ni;
            if (n < N) {
                int t = node_type[n];
                float4 o;
                if (t <= 1) {   // UPDATE_NODE_TYPES = (0,1); types are 0..2
                    o = make_float4(acc3[ni][0], acc3[ni][1], acc3[ni][2], acc3[ni][3]);
                } else {
                    o = *(const float4*)&X[(size_t)n * D + j43];
                }
                *(float4*)&out[(size_t)n * D + j43] = o;
            }
        }
    }
}

extern "C" void kernel_launch(void* const* d_in, const int* in_sizes, int n_in,
                              void* d_out, int out_size, void* d_ws, size_t ws_size,
                              hipStream_t stream) {
    const float* X     = (const float*)d_in[0];
    const int*   src   = (const int*)d_in[1];
    const int*   dst   = (const int*)d_in[2];
    const int*   etype = (const int*)d_in[3];
    const int*   ntype = (const int*)d_in[4];
    const float* W1    = (const float*)d_in[5];
    const float* b1    = (const float*)d_in[6];
    const float* W2    = (const float*)d_in[7];
    const float* b2    = (const float*)d_in[8];
    const float* W3    = (const float*)d_in[9];
    const float* b3    = (const float*)d_in[10];
    const float* Wu1   = (const float*)d_in[11];
    const float* bu1   = (const float*)d_in[12];
    const float* Wu2   = (const float*)d_in[13];
    const float* bu2   = (const float*)d_in[14];
    const float* Wu3   = (const float*)d_in[15];
    const float* bu3   = (const float*)d_in[16];
    float* out = (float*)d_out;

    const int N = in_sizes[4];   // node_type length
    const int E = in_sizes[1];   // src length

    // workspace layout
    float* U    = (float*)d_ws;                       // N * R * H floats (51.2 MB)
    float* S    = U + (size_t)N * R * H;              // N * H floats (12.8 MB)
    int* cnt    = (int*)(S + (size_t)N * H);          // N
    int* offs   = cnt + N;                            // N
    int* cursor = offs + N;                           // N
    int* eidx   = cursor + N;                         // E

    hipMemsetAsync(cnt, 0, (size_t)N * sizeof(int), stream);

    int eb = (E + 255) / 256;
    k_count<<<eb, 256, 0, stream>>>(dst, cnt, E);
    k_scan<<<1, 1024, 0, stream>>>(cnt, offs, cursor, N);
    k_fill<<<eb, 256, 0, stream>>>(src, dst, etype, cursor, eidx, E);

    int tiles = (N + NT - 1) / NT;
    k_mlp_rel<<<tiles * R, 256, 0, stream>>>(X, W1, b1, W2, b2, W3, b3, Wu1, U, N);
    k_gather<<<(N + 3) / 4, 256, 0, stream>>>(U, cnt, offs, eidx, S, N);
    k_upd<<<tiles, 256, 0, stream>>>(X, S, cnt, ntype,
                                     Wu1, bu1, Wu2, bu2, Wu3, bu3, out, N);
}